// Round 11
// baseline (191.156 us; speedup 1.0000x reference)
//
#include <hip/hip_runtime.h>

// LMMD loss, round 11 = round 10 aux + wave-self-sufficient barrier-free k3.
// Each wave stages ONLY its own A-half (rows wr..wr+63) and B-half (wc..wc+63)
// into wave-private LDS via GLD16, waits with a wave-local s_waitcnt vmcnt(0)
// (NOT a barrier), and MFMAs. Zero __syncthreads in the K-loop -> waves
// desynchronize and cover each other's L2 latency. Redundant 2x fetch per
// half is L2-absorbed.
// loss = (1/n_idx) * sum_{p<=q} f_pq * w_pq * K(p,q),  f=2 off-diag, 1 diag
// Features: bf16 MFMA (hi-only; exact-match verified rounds 2-10).
// Weights: SS lookup (exact) / ST LDS gather (bf16) / TT precomputed bf16 tiles.

#define B 4096
#define D 256
#define C 31
#define N2 8192
#define NTILE 64                       // 128-row tiles over 2B rows
#define NBLK (NTILE * (NTILE + 1) / 2) // 2080
#define NTT (32 * 33 / 2)              // 528 TT tile pairs

typedef __attribute__((ext_vector_type(8))) short bf16x8;
typedef __attribute__((ext_vector_type(4))) float f32x4;

struct WS {
  double acc_loss;
  double sum_sq;
  double Msum[256];  // column sums of total (double atomics)
  int s_cnt[32];
  float t_cnt[32];
  int t_pres[32];
  float s_div[32], t_div[32];
  float inv_n_idx;
  float inv_d4;
  float sq[N2];
  int slab[N2];
  float sdv[N2];
  alignas(16) unsigned short Thi[(size_t)N2 * D];   // bf16 features (linear)
  alignas(16) unsigned short vhi[(size_t)N2 * 32];  // bf16 v rows (linear)
  alignas(16) float v[(size_t)N2 * 32];             // exact f32 v rows
  alignas(16) unsigned short wtt[(size_t)NTT * 16384];  // bf16 TT weight tiles
};

static __device__ __forceinline__ unsigned short f2bf(float f) {
  unsigned int u = __float_as_uint(f);
  return (unsigned short)((u + 0x7fffu + ((u >> 16) & 1u)) >> 16);  // RNE
}
static __device__ __forceinline__ float bf2f(unsigned short s) {
  return __uint_as_float(((unsigned int)s) << 16);
}

#define GLD16(gsrc, ldst)                                                     \
  __builtin_amdgcn_global_load_lds(                                           \
      (const __attribute__((address_space(1))) void*)(gsrc),                  \
      (__attribute__((address_space(3))) void*)(ldst), 16, 0, 0)

__global__ void k0_init(WS* __restrict__ ws) {
  int tid = threadIdx.x;  // 256
  if (tid == 0) { ws->acc_loss = 0.0; ws->sum_sq = 0.0; }
  if (tid < 32) {
    ws->s_cnt[tid] = 0;
    ws->t_cnt[tid] = 0.f;
    ws->t_pres[tid] = 0;
  }
  ws->Msum[tid] = 0.0;
}

__global__ void kA1_stats(const int* __restrict__ s_label,
                          const float* __restrict__ t_label,
                          WS* __restrict__ ws) {
  __shared__ int ls[32];
  __shared__ float lt[32];
  __shared__ int lpres[32];
  int tid = threadIdx.x, lane = tid & 63;  // 256, 16 blocks
  if (tid < 32) { ls[tid] = 0; lt[tid] = 0.f; lpres[tid] = 0; }
  __syncthreads();
  int row = blockIdx.x * 256 + tid;
  atomicAdd(&ls[s_label[row]], 1);
  const float* r = t_label + (size_t)row * C;
  float best = -1e30f;
  int barg = 0;
#pragma unroll
  for (int c = 0; c < C; ++c) {
    float x = r[c];
    if (x > best) { best = x; barg = c; }  // first-max == jnp.argmax
    float s = x;
#pragma unroll
    for (int off = 32; off; off >>= 1) s += __shfl_down(s, off, 64);
    if (lane == 0) atomicAdd(&lt[c], s);
  }
  lpres[barg] = 1;  // benign race
  __syncthreads();
  if (tid < 32) {
    if (ls[tid]) atomicAdd(&ws->s_cnt[tid], ls[tid]);
    atomicAdd(&ws->t_cnt[tid], lt[tid]);
    if (lpres[tid]) ws->t_pres[tid] = 1;
  }
}

__global__ void kA2_final(WS* __restrict__ ws) {
  int tid = threadIdx.x;  // 64
  int m = 0;
  if (tid < 32) {
    int cnt = ws->s_cnt[tid];
    m = (tid < C) && (cnt > 0) && (ws->t_pres[tid] != 0);
    ws->s_div[tid] = m ? 1.f / (float)cnt : 0.f;
    float t = ws->t_cnt[tid];
    float ta = (t == 0.f) ? 100.f : t;
    ws->t_div[tid] = m ? 1.f / ta : 0.f;
  }
  unsigned long long bal = __ballot(m);
  if (tid == 0) ws->inv_n_idx = 1.f / fmaxf((float)__popcll(bal), 1.f);
}

__global__ __launch_bounds__(256) void kB_prep(const float* __restrict__ src,
                                               const float* __restrict__ tgt,
                                               const int* __restrict__ s_label,
                                               const float* __restrict__ t_label,
                                               WS* __restrict__ ws) {
  int tid = threadIdx.x, w = tid >> 6, lane = tid & 63;
  int r0 = blockIdx.x * 32;
  __shared__ float rsq[32];
  __shared__ float colp[4][256];
  float ca0 = 0.f, ca1 = 0.f, ca2 = 0.f, ca3 = 0.f;
#pragma unroll
  for (int i = 0; i < 8; ++i) {
    int rr = w * 8 + i;
    int p = r0 + rr;
    const float* rp = (p < B) ? src + (size_t)p * D : tgt + (size_t)(p - B) * D;
    float4 x = *(const float4*)(rp + lane * 4);
    ushort4 hv;
    hv.x = f2bf(x.x); hv.y = f2bf(x.y); hv.z = f2bf(x.z); hv.w = f2bf(x.w);
    *(ushort4*)(&ws->Thi[(size_t)p * D + lane * 4]) = hv;  // linear layout
    ca0 += x.x; ca1 += x.y; ca2 += x.z; ca3 += x.w;
    float s = x.x * x.x + x.y * x.y + x.z * x.z + x.w * x.w;
#pragma unroll
    for (int off = 32; off; off >>= 1) s += __shfl_down(s, off, 64);
    if (lane == 0) rsq[rr] = s;
  }
  colp[w][lane * 4 + 0] = ca0;
  colp[w][lane * 4 + 1] = ca1;
  colp[w][lane * 4 + 2] = ca2;
  colp[w][lane * 4 + 3] = ca3;
  __syncthreads();
  if (tid < 32) {
    int p = r0 + tid;
    ws->sq[p] = rsq[tid];
    if (p < B) {
      int lb = s_label[p];
      ws->slab[p] = lb;
      ws->sdv[p] = ws->s_div[lb];
    } else {
      ws->slab[p] = 0;
      ws->sdv[p] = 0.f;
    }
  }
  // block sum of sq -> one double atomic (wave 0, all 64 lanes active)
  if (tid < 64) {
    float ss = (tid < 32) ? rsq[tid] : 0.f;
#pragma unroll
    for (int off = 32; off; off >>= 1) ss += __shfl_down(ss, off, 64);
    if (tid == 0) atomicAdd(&ws->sum_sq, (double)ss);
  }
  // column sums -> 256 double atomics per block
  atomicAdd(&ws->Msum[tid],
            (double)(colp[0][tid] + colp[1][tid] + colp[2][tid] + colp[3][tid]));
  int vr = tid >> 3, cb = (tid & 7) * 4;
  int p = r0 + vr;
  float vals[4];
#pragma unroll
  for (int j = 0; j < 4; ++j) {
    int c = cb + j;
    float val = 0.f;
    if (c < C) {
      if (p < B)
        val = (s_label[p] == c) ? ws->s_div[c] : 0.f;
      else
        val = -t_label[(size_t)(p - B) * C + c] * ws->t_div[c];
    }
    vals[j] = val;
  }
  float4 vf; vf.x = vals[0]; vf.y = vals[1]; vf.z = vals[2]; vf.w = vals[3];
  *(float4*)(&ws->v[(size_t)p * 32 + cb]) = vf;
  ushort4 vh;
  vh.x = f2bf(vals[0]); vh.y = f2bf(vals[1]);
  vh.z = f2bf(vals[2]); vh.w = f2bf(vals[3]);
  *(ushort4*)(&ws->vhi[(size_t)p * 32 + cb]) = vh;
}

// One wave: inv_d4 from sum_sq and Msum.
__global__ void kC_bw(WS* __restrict__ ws) {
  int lane = threadIdx.x;  // 64
  double msq = 0.0;
#pragma unroll
  for (int i = 0; i < 4; ++i) {
    double m = ws->Msum[i * 64 + lane];
    msq += m * m;
  }
#pragma unroll
  for (int off = 32; off; off >>= 1) msq += __shfl_down(msq, off, 64);
  if (lane == 0) {
    double S = ws->sum_sq;
    double n = (double)N2;
    double sum_l2 = 2.0 * n * S - 2.0 * msq;
    double bw = sum_l2 / (n * n - n);
    bw = fmax(bw, 1e-6) * 0.25;          // / KERNEL_MUL^2
    double dc4 = fmax(bw * 16.0, 1e-6);  // largest denom
    ws->inv_d4 = (float)(1.0 / dc4);
  }
}

// Precompute TT weight tiles (bf16, stored in C-fragment order). vhi is linear.
__global__ __launch_bounds__(256, 2) void kW_tt(WS* __restrict__ ws) {
  int tid = threadIdx.x, w = tid >> 6, lane = tid & 63;
  int lin = blockIdx.x;
  int tp = 0;
  while (32 * (tp + 1) - ((tp + 1) * tp) / 2 <= lin) ++tp;
  int tq = tp + (lin - (32 * tp - (tp * (tp - 1)) / 2));
  int p0 = B + tp * 128, q0 = B + tq * 128;

  __shared__ __align__(16) unsigned short Ash[128 * 32];
  __shared__ __align__(16) unsigned short Bsh[128 * 32];
  const int wr = (w >> 1) * 64, wc = (w & 1) * 64;
  const int mrow = lane & 15, quad = lane >> 4;
  f32x4 acc[4][4];
#pragma unroll
  for (int i = 0; i < 4; ++i)
#pragma unroll
    for (int j = 0; j < 4; ++j) acc[i][j] = (f32x4){0.f, 0.f, 0.f, 0.f};

  int rA = tid >> 2, cp8 = (tid & 3) * 8;
  unsigned short* ldsA = Ash + w * 512;
  unsigned short* ldsB = Bsh + w * 512;
  const unsigned short* gA = ws->vhi + (size_t)(p0 + rA) * 32 + cp8;
  const unsigned short* gB = ws->vhi + (size_t)(q0 + rA) * 32 + cp8;
  GLD16(gA, ldsA);
  GLD16(gA + (size_t)64 * 32, ldsA + 2048);
  GLD16(gB, ldsB);
  GLD16(gB + (size_t)64 * 32, ldsB + 2048);
  __syncthreads();
  {
    bf16x8 af[4], bfr[4];
#pragma unroll
    for (int ti = 0; ti < 4; ++ti)
      af[ti] = *(const bf16x8*)(Ash + (wr + ti * 16 + mrow) * 32 + quad * 8);
#pragma unroll
    for (int tj = 0; tj < 4; ++tj)
      bfr[tj] = *(const bf16x8*)(Bsh + (wc + tj * 16 + mrow) * 32 + quad * 8);
#pragma unroll
    for (int ti = 0; ti < 4; ++ti)
#pragma unroll
      for (int tj = 0; tj < 4; ++tj)
        acc[ti][tj] = __builtin_amdgcn_mfma_f32_16x16x32_bf16(
            af[ti], bfr[tj], acc[ti][tj], 0, 0, 0);
  }
  unsigned short* out = ws->wtt + (size_t)lin * 16384 + tid * 64;
#pragma unroll
  for (int ti = 0; ti < 4; ++ti)
#pragma unroll
    for (int tj = 0; tj < 4; ++tj) {
      ushort4 u;
      u.x = f2bf(acc[ti][tj][0]);
      u.y = f2bf(acc[ti][tj][1]);
      u.z = f2bf(acc[ti][tj][2]);
      u.w = f2bf(acc[ti][tj][3]);
      *(ushort4*)(out + (ti * 4 + tj) * 4) = u;
    }
}

// ---- epilogue helpers (forceinlined; KIND 0=SS, 1=ST) ----
template <int KIND, bool DIAG>
static __device__ __forceinline__ float epi_ss_st(
    const f32x4 (&acc)[4][4], const WS* __restrict__ ws,
    const unsigned short* Vsw, int p0, int q0, int wr, int wc, int mrow,
    int quad) {
  float cinv = ws->inv_d4;
  float k2 = 2.f * cinv;
  float cq[4], sdq[4];
  int lq[4];
#pragma unroll
  for (int tj = 0; tj < 4; ++tj) {
    int q = q0 + wc + tj * 16 + mrow;
    cq[tj] = -cinv * ws->sq[q];
    if (KIND == 0) {
      lq[tj] = ws->slab[q];
      sdq[tj] = ws->sdv[q];
    }
  }
  float local = 0.f;
#pragma unroll
  for (int ti = 0; ti < 4; ++ti) {
#pragma unroll
    for (int rg = 0; rg < 4; ++rg) {
      int p = p0 + wr + ti * 16 + quad * 4 + rg;
      float cpl = -cinv * ws->sq[p];
      int lp = ws->slab[p];
      float sp = ws->sdv[p];
#pragma unroll
      for (int tj = 0; tj < 4; ++tj) {
        float z = fminf(fmaf(k2, acc[ti][tj][rg], cpl + cq[tj]), 0.f);
        float y = __expf(z);
        float kv = y;
        y *= y; kv += y;
        y *= y; kv += y;
        y *= y; kv += y;
        y *= y; kv += y;
        float wv;
        if (KIND == 0) {
          wv = (lp == lq[tj]) ? sp * sdq[tj] : 0.f;
        } else {
          int ql = wc + tj * 16 + mrow;
          wv = sp * bf2f(Vsw[ql * 32 + ((lp + ql) & 31)]);
        }
        if (DIAG) {
          int q = q0 + wc + tj * 16 + mrow;
          float f = (q > p) ? 2.f : ((q == p) ? 1.f : 0.f);
          local = fmaf(wv * f, kv, local);
        } else {
          local = fmaf(wv, kv, local);
        }
      }
    }
  }
  if (!DIAG) local *= 2.f;
  return local;
}

template <bool DIAG>
static __device__ __forceinline__ float epi_tt(const f32x4 (&acc)[4][4],
                                               const WS* __restrict__ ws,
                                               const unsigned short* wttp,
                                               int p0, int q0, int wr, int wc,
                                               int mrow, int quad) {
  float cinv = ws->inv_d4;
  float k2 = 2.f * cinv;
  float cq[4];
#pragma unroll
  for (int tj = 0; tj < 4; ++tj)
    cq[tj] = -cinv * ws->sq[q0 + wc + tj * 16 + mrow];
  float cp[16];
#pragma unroll
  for (int ti = 0; ti < 4; ++ti)
#pragma unroll
    for (int rg = 0; rg < 4; ++rg)
      cp[ti * 4 + rg] = -cinv * ws->sq[p0 + wr + ti * 16 + quad * 4 + rg];
  float local = 0.f;
#pragma unroll
  for (int ti = 0; ti < 4; ++ti) {
#pragma unroll
    for (int tj = 0; tj < 4; ++tj) {
      ushort4 u = *(const ushort4*)(wttp + (ti * 4 + tj) * 4);
      float wf[4] = {bf2f(u.x), bf2f(u.y), bf2f(u.z), bf2f(u.w)};
#pragma unroll
      for (int rg = 0; rg < 4; ++rg) {
        float z = fminf(fmaf(k2, acc[ti][tj][rg], cp[ti * 4 + rg] + cq[tj]), 0.f);
        float y = __expf(z);
        float kv = y;
        y *= y; kv += y;
        y *= y; kv += y;
        y *= y; kv += y;
        y *= y; kv += y;
        if (DIAG) {
          int p = p0 + wr + ti * 16 + quad * 4 + rg;
          int q = q0 + wc + tj * 16 + mrow;
          float f = (q > p) ? 2.f : ((q == p) ? 1.f : 0.f);
          local = fmaf(wf[rg] * f, kv, local);
        } else {
          local = fmaf(wf[rg], kv, local);
        }
      }
    }
  }
  if (!DIAG) local *= 2.f;
  return local;
}

// Merged main kernel: wave-self-sufficient barrier-free K-loop.
__global__ __launch_bounds__(256, 4) void k3_main(WS* __restrict__ ws) {
  int tid = threadIdx.x, w = tid >> 6, lane = tid & 63;
  int lin0 = blockIdx.x;
  int e = (lin0 & 7) * (NBLK / 8) + (lin0 >> 3);
  int b = 0, nb = 484, rem = e;
  while (rem >= nb) { rem -= nb; ++b; nb -= 64; }
  int base = b * 8;
  int bq_, r;
  if (rem < 36) {  // triangular head of the band (bq within band)
    bq_ = 0;
    while ((bq_ + 1) * (bq_ + 2) / 2 <= rem) ++bq_;
    r = rem - (bq_ * (bq_ + 1)) / 2;
  } else {  // full-height 8-row columns
    int t = rem - 36;
    bq_ = 8 + (t >> 3);
    r = t & 7;
  }
  int bp = base + r, bq = base + bq_;
  int p0 = bp * 128, q0 = bq * 128;

  __shared__ __align__(16) unsigned short Asw[4][64 * 32];  // 16 KB wave-priv A
  __shared__ __align__(16) unsigned short Bsw[4][64 * 32];  // 16 KB wave-priv B
  __shared__ unsigned short Vsw[128 * 32];                  // 8 KB (ST only)
  // total 40960 B -> 4 blocks/CU; reduction scratch aliases Vsw post-barrier

  const int wr = (w >> 1) * 64, wc = (w & 1) * 64;
  const int mrow = lane & 15, quad = lane >> 4;

  bool is_ss = (bq < 32);
  bool is_tt = (bp >= 32);
  if (!is_ss && !is_tt) {
    // ST: stage rotate-swizzled bf16 v rows BEFORE the K-loop; one barrier.
    int rr = tid >> 1, h = (tid & 1) * 16;
    const float* vrow = ws->v + (size_t)(q0 + rr) * 32 + h;
#pragma unroll
    for (int j = 0; j < 16; ++j)
      Vsw[rr * 32 + ((h + j + rr) & 31)] = f2bf(vrow[j]);
    __syncthreads();  // block-uniform condition -> no divergence hazard
  }

  f32x4 acc[4][4];
#pragma unroll
  for (int i = 0; i < 4; ++i)
#pragma unroll
    for (int j = 0; j < 4; ++j) acc[i][j] = (f32x4){0.f, 0.f, 0.f, 0.f};

  const unsigned short* Thi = ws->Thi;
  // per-lane staging source pointers: lane l covers row (l>>2), quad (l&3)
  const unsigned short* gA =
      Thi + (size_t)(p0 + wr + (lane >> 2)) * D + (lane & 3) * 8;
  const unsigned short* gB =
      Thi + (size_t)(q0 + wc + (lane >> 2)) * D + (lane & 3) * 8;
  unsigned short* AswW = Asw[w];  // wave-uniform base
  unsigned short* BswW = Bsw[w];

#pragma unroll
  for (int c = 0; c < 8; ++c) {
#pragma unroll
    for (int g = 0; g < 4; ++g) {  // 4 GLD16 each = 64 rows x 32 k shorts
      GLD16(gA + (size_t)(g * 16) * D + c * 32, AswW + g * 512);
      GLD16(gB + (size_t)(g * 16) * D + c * 32, BswW + g * 512);
    }
    __builtin_amdgcn_s_waitcnt(0x0F70);  // vmcnt(0) only — wave-local, no barrier
    bf16x8 af[4], bfr[4];
#pragma unroll
    for (int ti = 0; ti < 4; ++ti)
      af[ti] = *(const bf16x8*)(AswW + (ti * 16 + mrow) * 32 + quad * 8);
#pragma unroll
    for (int tj = 0; tj < 4; ++tj)
      bfr[tj] = *(const bf16x8*)(BswW + (tj * 16 + mrow) * 32 + quad * 8);
#pragma unroll
    for (int ti = 0; ti < 4; ++ti)
#pragma unroll
      for (int tj = 0; tj < 4; ++tj)
        acc[ti][tj] = __builtin_amdgcn_mfma_f32_16x16x32_bf16(
            af[ti], bfr[tj], acc[ti][tj], 0, 0, 0);
  }

  float local;
  if (is_ss) {
    if (bp == bq)
      local = epi_ss_st<0, true>(acc, ws, Vsw, p0, q0, wr, wc, mrow, quad);
    else
      local = epi_ss_st<0, false>(acc, ws, Vsw, p0, q0, wr, wc, mrow, quad);
  } else if (!is_tt) {
    local = epi_ss_st<1, false>(acc, ws, Vsw, p0, q0, wr, wc, mrow, quad);
  } else {
    int tp = bp - 32, tq = bq - 32;
    int ttlin = 32 * tp - (tp * (tp - 1)) / 2 + (tq - tp);
    const unsigned short* wttp = ws->wtt + (size_t)ttlin * 16384 + tid * 64;
    if (bp == bq)
      local = epi_tt<true>(acc, ws, wttp, p0, q0, wr, wc, mrow, quad);
    else
      local = epi_tt<false>(acc, ws, wttp, p0, q0, wr, wc, mrow, quad);
  }

  double dl = (double)local;
#pragma unroll
  for (int off = 32; off; off >>= 1) dl += __shfl_down(dl, off, 64);
  __syncthreads();  // all epilogue Vsw reads done before redv overwrite
  double* redv = (double*)Vsw;
  if (lane == 0) redv[w] = dl;
  __syncthreads();
  if (tid == 0) atomicAdd(&ws->acc_loss, redv[0] + redv[1] + redv[2] + redv[3]);
}

__global__ void k4_out(WS* __restrict__ ws, float* __restrict__ out) {
  out[0] = (float)(ws->acc_loss * (double)ws->inv_n_idx);
}

extern "C" void kernel_launch(void* const* d_in, const int* in_sizes, int n_in,
                              void* d_out, int out_size, void* d_ws, size_t ws_size,
                              hipStream_t stream) {
  const float* src = (const float*)d_in[0];
  const float* tgt = (const float*)d_in[1];
  const int* s_label = (const int*)d_in[2];
  const float* t_label = (const float*)d_in[3];
  float* out = (float*)d_out;
  WS* ws = (WS*)d_ws;  // ~23 MB

  k0_init<<<1, 256, 0, stream>>>(ws);
  kA1_stats<<<16, 256, 0, stream>>>(s_label, t_label, ws);
  kA2_final<<<1, 64, 0, stream>>>(ws);
  kB_prep<<<256, 256, 0, stream>>>(src, tgt, s_label, t_label, ws);
  kC_bw<<<1, 64, 0, stream>>>(ws);
  kW_tt<<<NTT, 256, 0, stream>>>(ws);
  k3_main<<<NBLK, 256, 0, stream>>>(ws);
  k4_out<<<1, 1, 0, stream>>>(ws, out);
}

// Round 12
// 172.361 us; speedup vs baseline: 1.1090x; 1.1090x over previous
//
#include <hip/hip_runtime.h>

// LMMD loss, round 12 = round 10 skeleton with fp8-e4m3 feature path.
// Feature rows are 256 B (fp8) instead of 512 B (bf16): the identical staging
// geometry (64 B/row/chunk, 2 chunks per barrier pair) now covers K=128 per
// stage -> 2 barrier-drain pairs instead of 4, 16 GLD16 instead of 32.
// MFMA count unchanged (mfma_f32_16x16x32_fp8_fp8 = bf16 rate).
// loss = (1/n_idx) * sum_{p<=q} f_pq * w_pq * K(p,q),  f=2 off-diag, 1 diag
// Weights: SS lookup (exact) / ST LDS gather (bf16) / TT precomputed bf16 tiles.

#define B 4096
#define D 256
#define C 31
#define N2 8192
#define NTILE 64                       // 128-row tiles over 2B rows
#define NBLK (NTILE * (NTILE + 1) / 2) // 2080
#define NTT (32 * 33 / 2)              // 528 TT tile pairs

typedef __attribute__((ext_vector_type(8))) short bf16x8;
typedef __attribute__((ext_vector_type(4))) float f32x4;

struct WS {
  double acc_loss;
  double sum_sq;
  double Msum[256];  // column sums of total (double atomics)
  int s_cnt[32];
  float t_cnt[32];
  int t_pres[32];
  float s_div[32], t_div[32];
  float inv_n_idx;
  float inv_d4;
  float sq[N2];
  int slab[N2];
  float sdv[N2];
  alignas(16) unsigned char Thi8[(size_t)N2 * D];   // fp8 e4m3 features
  alignas(16) unsigned short vhi[(size_t)N2 * 32];  // bf16 v rows (linear)
  alignas(16) float v[(size_t)N2 * 32];             // exact f32 v rows
  alignas(16) unsigned short wtt[(size_t)NTT * 16384];  // bf16 TT weight tiles
};

static __device__ __forceinline__ unsigned short f2bf(float f) {
  unsigned int u = __float_as_uint(f);
  return (unsigned short)((u + 0x7fffu + ((u >> 16) & 1u)) >> 16);  // RNE
}
static __device__ __forceinline__ float bf2f(unsigned short s) {
  return __uint_as_float(((unsigned int)s) << 16);
}

#define GLD16(gsrc, ldst)                                                     \
  __builtin_amdgcn_global_load_lds(                                           \
      (const __attribute__((address_space(1))) void*)(gsrc),                  \
      (__attribute__((address_space(3))) void*)(ldst), 16, 0, 0)

__global__ void k0_init(WS* __restrict__ ws) {
  int tid = threadIdx.x;  // 256
  if (tid == 0) { ws->acc_loss = 0.0; ws->sum_sq = 0.0; }
  if (tid < 32) {
    ws->s_cnt[tid] = 0;
    ws->t_cnt[tid] = 0.f;
    ws->t_pres[tid] = 0;
  }
  ws->Msum[tid] = 0.0;
}

__global__ void kA1_stats(const int* __restrict__ s_label,
                          const float* __restrict__ t_label,
                          WS* __restrict__ ws) {
  __shared__ int ls[32];
  __shared__ float lt[32];
  __shared__ int lpres[32];
  int tid = threadIdx.x, lane = tid & 63;  // 256, 16 blocks
  if (tid < 32) { ls[tid] = 0; lt[tid] = 0.f; lpres[tid] = 0; }
  __syncthreads();
  int row = blockIdx.x * 256 + tid;
  atomicAdd(&ls[s_label[row]], 1);
  const float* r = t_label + (size_t)row * C;
  float best = -1e30f;
  int barg = 0;
#pragma unroll
  for (int c = 0; c < C; ++c) {
    float x = r[c];
    if (x > best) { best = x; barg = c; }  // first-max == jnp.argmax
    float s = x;
#pragma unroll
    for (int off = 32; off; off >>= 1) s += __shfl_down(s, off, 64);
    if (lane == 0) atomicAdd(&lt[c], s);
  }
  lpres[barg] = 1;  // benign race
  __syncthreads();
  if (tid < 32) {
    if (ls[tid]) atomicAdd(&ws->s_cnt[tid], ls[tid]);
    atomicAdd(&ws->t_cnt[tid], lt[tid]);
    if (lpres[tid]) ws->t_pres[tid] = 1;
  }
}

__global__ void kA2_final(WS* __restrict__ ws) {
  int tid = threadIdx.x;  // 64
  int m = 0;
  if (tid < 32) {
    int cnt = ws->s_cnt[tid];
    m = (tid < C) && (cnt > 0) && (ws->t_pres[tid] != 0);
    ws->s_div[tid] = m ? 1.f / (float)cnt : 0.f;
    float t = ws->t_cnt[tid];
    float ta = (t == 0.f) ? 100.f : t;
    ws->t_div[tid] = m ? 1.f / ta : 0.f;
  }
  unsigned long long bal = __ballot(m);
  if (tid == 0) ws->inv_n_idx = 1.f / fmaxf((float)__popcll(bal), 1.f);
}

__global__ __launch_bounds__(256) void kB_prep(const float* __restrict__ src,
                                               const float* __restrict__ tgt,
                                               const int* __restrict__ s_label,
                                               const float* __restrict__ t_label,
                                               WS* __restrict__ ws) {
  int tid = threadIdx.x, w = tid >> 6, lane = tid & 63;
  int r0 = blockIdx.x * 32;
  __shared__ float rsq[32];
  __shared__ float colp[4][256];
  float ca0 = 0.f, ca1 = 0.f, ca2 = 0.f, ca3 = 0.f;
#pragma unroll
  for (int i = 0; i < 8; ++i) {
    int rr = w * 8 + i;
    int p = r0 + rr;
    const float* rp = (p < B) ? src + (size_t)p * D : tgt + (size_t)(p - B) * D;
    float4 x = *(const float4*)(rp + lane * 4);
    // fp8 e4m3 pack: byte0=x.x .. byte3=x.w (HW cvt)
    unsigned int pk = __builtin_amdgcn_cvt_pk_fp8_f32(x.x, x.y, 0, false);
    pk = __builtin_amdgcn_cvt_pk_fp8_f32(x.z, x.w, pk, true);
    *(unsigned int*)(&ws->Thi8[(size_t)p * D + lane * 4]) = pk;
    ca0 += x.x; ca1 += x.y; ca2 += x.z; ca3 += x.w;
    float s = x.x * x.x + x.y * x.y + x.z * x.z + x.w * x.w;
#pragma unroll
    for (int off = 32; off; off >>= 1) s += __shfl_down(s, off, 64);
    if (lane == 0) rsq[rr] = s;
  }
  colp[w][lane * 4 + 0] = ca0;
  colp[w][lane * 4 + 1] = ca1;
  colp[w][lane * 4 + 2] = ca2;
  colp[w][lane * 4 + 3] = ca3;
  __syncthreads();
  if (tid < 32) {
    int p = r0 + tid;
    ws->sq[p] = rsq[tid];
    if (p < B) {
      int lb = s_label[p];
      ws->slab[p] = lb;
      ws->sdv[p] = ws->s_div[lb];
    } else {
      ws->slab[p] = 0;
      ws->sdv[p] = 0.f;
    }
  }
  // block sum of sq -> one double atomic (wave 0, all 64 lanes active)
  if (tid < 64) {
    float ss = (tid < 32) ? rsq[tid] : 0.f;
#pragma unroll
    for (int off = 32; off; off >>= 1) ss += __shfl_down(ss, off, 64);
    if (tid == 0) atomicAdd(&ws->sum_sq, (double)ss);
  }
  // column sums -> 256 double atomics per block
  atomicAdd(&ws->Msum[tid],
            (double)(colp[0][tid] + colp[1][tid] + colp[2][tid] + colp[3][tid]));
  int vr = tid >> 3, cb = (tid & 7) * 4;
  int p = r0 + vr;
  float vals[4];
#pragma unroll
  for (int j = 0; j < 4; ++j) {
    int c = cb + j;
    float val = 0.f;
    if (c < C) {
      if (p < B)
        val = (s_label[p] == c) ? ws->s_div[c] : 0.f;
      else
        val = -t_label[(size_t)(p - B) * C + c] * ws->t_div[c];
    }
    vals[j] = val;
  }
  float4 vf; vf.x = vals[0]; vf.y = vals[1]; vf.z = vals[2]; vf.w = vals[3];
  *(float4*)(&ws->v[(size_t)p * 32 + cb]) = vf;
  ushort4 vh;
  vh.x = f2bf(vals[0]); vh.y = f2bf(vals[1]);
  vh.z = f2bf(vals[2]); vh.w = f2bf(vals[3]);
  *(ushort4*)(&ws->vhi[(size_t)p * 32 + cb]) = vh;
}

// One wave: inv_d4 from sum_sq and Msum.
__global__ void kC_bw(WS* __restrict__ ws) {
  int lane = threadIdx.x;  // 64
  double msq = 0.0;
#pragma unroll
  for (int i = 0; i < 4; ++i) {
    double m = ws->Msum[i * 64 + lane];
    msq += m * m;
  }
#pragma unroll
  for (int off = 32; off; off >>= 1) msq += __shfl_down(msq, off, 64);
  if (lane == 0) {
    double S = ws->sum_sq;
    double n = (double)N2;
    double sum_l2 = 2.0 * n * S - 2.0 * msq;
    double bw = sum_l2 / (n * n - n);
    bw = fmax(bw, 1e-6) * 0.25;          // / KERNEL_MUL^2
    double dc4 = fmax(bw * 16.0, 1e-6);  // largest denom
    ws->inv_d4 = (float)(1.0 / dc4);
  }
}

// Precompute TT weight tiles (bf16, stored in C-fragment order). vhi is linear.
__global__ __launch_bounds__(256, 2) void kW_tt(WS* __restrict__ ws) {
  int tid = threadIdx.x, w = tid >> 6, lane = tid & 63;
  int lin = blockIdx.x;
  int tp = 0;
  while (32 * (tp + 1) - ((tp + 1) * tp) / 2 <= lin) ++tp;
  int tq = tp + (lin - (32 * tp - (tp * (tp - 1)) / 2));
  int p0 = B + tp * 128, q0 = B + tq * 128;

  __shared__ __align__(16) unsigned short Ash[128 * 32];
  __shared__ __align__(16) unsigned short Bsh[128 * 32];
  const int wr = (w >> 1) * 64, wc = (w & 1) * 64;
  const int mrow = lane & 15, quad = lane >> 4;
  f32x4 acc[4][4];
#pragma unroll
  for (int i = 0; i < 4; ++i)
#pragma unroll
    for (int j = 0; j < 4; ++j) acc[i][j] = (f32x4){0.f, 0.f, 0.f, 0.f};

  int rA = tid >> 2, cp8 = (tid & 3) * 8;
  unsigned short* ldsA = Ash + w * 512;
  unsigned short* ldsB = Bsh + w * 512;
  const unsigned short* gA = ws->vhi + (size_t)(p0 + rA) * 32 + cp8;
  const unsigned short* gB = ws->vhi + (size_t)(q0 + rA) * 32 + cp8;
  GLD16(gA, ldsA);
  GLD16(gA + (size_t)64 * 32, ldsA + 2048);
  GLD16(gB, ldsB);
  GLD16(gB + (size_t)64 * 32, ldsB + 2048);
  __syncthreads();
  {
    bf16x8 af[4], bfr[4];
#pragma unroll
    for (int ti = 0; ti < 4; ++ti)
      af[ti] = *(const bf16x8*)(Ash + (wr + ti * 16 + mrow) * 32 + quad * 8);
#pragma unroll
    for (int tj = 0; tj < 4; ++tj)
      bfr[tj] = *(const bf16x8*)(Bsh + (wc + tj * 16 + mrow) * 32 + quad * 8);
#pragma unroll
    for (int ti = 0; ti < 4; ++ti)
#pragma unroll
      for (int tj = 0; tj < 4; ++tj)
        acc[ti][tj] = __builtin_amdgcn_mfma_f32_16x16x32_bf16(
            af[ti], bfr[tj], acc[ti][tj], 0, 0, 0);
  }
  unsigned short* out = ws->wtt + (size_t)lin * 16384 + tid * 64;
#pragma unroll
  for (int ti = 0; ti < 4; ++ti)
#pragma unroll
    for (int tj = 0; tj < 4; ++tj) {
      ushort4 u;
      u.x = f2bf(acc[ti][tj][0]);
      u.y = f2bf(acc[ti][tj][1]);
      u.z = f2bf(acc[ti][tj][2]);
      u.w = f2bf(acc[ti][tj][3]);
      *(ushort4*)(out + (ti * 4 + tj) * 4) = u;
    }
}

// ---- epilogue helpers (forceinlined; KIND 0=SS, 1=ST) ----
template <int KIND, bool DIAG>
static __device__ __forceinline__ float epi_ss_st(
    const f32x4 (&acc)[4][4], const WS* __restrict__ ws,
    const unsigned short* Vsw, int p0, int q0, int wr, int wc, int mrow,
    int quad) {
  float cinv = ws->inv_d4;
  float k2 = 2.f * cinv;
  float cq[4], sdq[4];
  int lq[4];
#pragma unroll
  for (int tj = 0; tj < 4; ++tj) {
    int q = q0 + wc + tj * 16 + mrow;
    cq[tj] = -cinv * ws->sq[q];
    if (KIND == 0) {
      lq[tj] = ws->slab[q];
      sdq[tj] = ws->sdv[q];
    }
  }
  float local = 0.f;
#pragma unroll
  for (int ti = 0; ti < 4; ++ti) {
#pragma unroll
    for (int rg = 0; rg < 4; ++rg) {
      int p = p0 + wr + ti * 16 + quad * 4 + rg;
      float cpl = -cinv * ws->sq[p];
      int lp = ws->slab[p];
      float sp = ws->sdv[p];
#pragma unroll
      for (int tj = 0; tj < 4; ++tj) {
        float z = fminf(fmaf(k2, acc[ti][tj][rg], cpl + cq[tj]), 0.f);
        float y = __expf(z);
        float kv = y;
        y *= y; kv += y;
        y *= y; kv += y;
        y *= y; kv += y;
        y *= y; kv += y;
        float wv;
        if (KIND == 0) {
          wv = (lp == lq[tj]) ? sp * sdq[tj] : 0.f;
        } else {
          int ql = wc + tj * 16 + mrow;
          wv = sp * bf2f(Vsw[ql * 32 + ((lp + ql) & 31)]);
        }
        if (DIAG) {
          int q = q0 + wc + tj * 16 + mrow;
          float f = (q > p) ? 2.f : ((q == p) ? 1.f : 0.f);
          local = fmaf(wv * f, kv, local);
        } else {
          local = fmaf(wv, kv, local);
        }
      }
    }
  }
  if (!DIAG) local *= 2.f;
  return local;
}

template <bool DIAG>
static __device__ __forceinline__ float epi_tt(const f32x4 (&acc)[4][4],
                                               const WS* __restrict__ ws,
                                               const unsigned short* wttp,
                                               int p0, int q0, int wr, int wc,
                                               int mrow, int quad) {
  float cinv = ws->inv_d4;
  float k2 = 2.f * cinv;
  float cq[4];
#pragma unroll
  for (int tj = 0; tj < 4; ++tj)
    cq[tj] = -cinv * ws->sq[q0 + wc + tj * 16 + mrow];
  float cp[16];
#pragma unroll
  for (int ti = 0; ti < 4; ++ti)
#pragma unroll
    for (int rg = 0; rg < 4; ++rg)
      cp[ti * 4 + rg] = -cinv * ws->sq[p0 + wr + ti * 16 + quad * 4 + rg];
  float local = 0.f;
#pragma unroll
  for (int ti = 0; ti < 4; ++ti) {
#pragma unroll
    for (int tj = 0; tj < 4; ++tj) {
      ushort4 u = *(const ushort4*)(wttp + (ti * 4 + tj) * 4);
      float wf[4] = {bf2f(u.x), bf2f(u.y), bf2f(u.z), bf2f(u.w)};
#pragma unroll
      for (int rg = 0; rg < 4; ++rg) {
        float z = fminf(fmaf(k2, acc[ti][tj][rg], cp[ti * 4 + rg] + cq[tj]), 0.f);
        float y = __expf(z);
        float kv = y;
        y *= y; kv += y;
        y *= y; kv += y;
        y *= y; kv += y;
        y *= y; kv += y;
        if (DIAG) {
          int p = p0 + wr + ti * 16 + quad * 4 + rg;
          int q = q0 + wc + tj * 16 + mrow;
          float f = (q > p) ? 2.f : ((q == p) ? 1.f : 0.f);
          local = fmaf(wf[rg] * f, kv, local);
        } else {
          local = fmaf(wf[rg], kv, local);
        }
      }
    }
  }
  if (!DIAG) local *= 2.f;
  return local;
}

// Merged main kernel: round-10 skeleton, fp8 feature path.
// 2 staging stages (K=128 each), 2 chunks per stage -> 2 barrier-drain pairs.
__global__ __launch_bounds__(256, 4) void k3_main(WS* __restrict__ ws) {
  int tid = threadIdx.x, w = tid >> 6, lane = tid & 63;
  int lin0 = blockIdx.x;
  int e = (lin0 & 7) * (NBLK / 8) + (lin0 >> 3);
  int b = 0, nb = 484, rem = e;
  while (rem >= nb) { rem -= nb; ++b; nb -= 64; }
  int base = b * 8;
  int bq_, r;
  if (rem < 36) {  // triangular head of the band (bq within band)
    bq_ = 0;
    while ((bq_ + 1) * (bq_ + 2) / 2 <= rem) ++bq_;
    r = rem - (bq_ * (bq_ + 1)) / 2;
  } else {  // full-height 8-row columns
    int t = rem - 36;
    bq_ = 8 + (t >> 3);
    r = t & 7;
  }
  int bp = base + r, bq = base + bq_;
  int p0 = bp * 128, q0 = bq * 128;

  __shared__ __align__(16) unsigned char Ash[2 * 128 * 64];  // 16 KB fp8 A
  __shared__ __align__(16) unsigned char Bsh[2 * 128 * 64];  // 16 KB fp8 B
  __shared__ unsigned short Vsw[128 * 32];                   // 8 KB (ST only)

  const int wr = (w >> 1) * 64, wc = (w & 1) * 64;
  const int mrow = lane & 15, quad = lane >> 4;
  f32x4 acc[4][4];
#pragma unroll
  for (int i = 0; i < 4; ++i)
#pragma unroll
    for (int j = 0; j < 4; ++j) acc[i][j] = (f32x4){0.f, 0.f, 0.f, 0.f};

  const unsigned char* T8 = ws->Thi8;
  int rA = tid >> 2, cb16 = (tid & 3) * 16;
  unsigned char* ldsA = Ash + w * 1024;
  unsigned char* ldsB = Bsh + w * 1024;

  for (int s = 0; s < 2; ++s) {
    int ks = s * 128;  // byte offset into the 256-B fp8 row
    __syncthreads();
#pragma unroll
    for (int c = 0; c < 2; ++c) {
      const unsigned char* gA =
          T8 + (size_t)(p0 + rA) * D + ks + c * 64 + cb16;
      GLD16(gA, ldsA + c * 8192);
      GLD16(gA + (size_t)64 * D, ldsA + c * 8192 + 4096);
      const unsigned char* gB =
          T8 + (size_t)(q0 + rA) * D + ks + c * 64 + cb16;
      GLD16(gB, ldsB + c * 8192);
      GLD16(gB + (size_t)64 * D, ldsB + c * 8192 + 4096);
    }
    __syncthreads();
#pragma unroll
    for (int c = 0; c < 2; ++c) {
#pragma unroll
      for (int t = 0; t < 2; ++t) {  // two K=32 fp8 MFMA steps per 64-B chunk
        long aF[4], bF[4];
#pragma unroll
        for (int ti = 0; ti < 4; ++ti)
          aF[ti] = *(const long*)(Ash + c * 8192 + (wr + ti * 16 + mrow) * 64 +
                                  t * 32 + quad * 8);
#pragma unroll
        for (int tj = 0; tj < 4; ++tj)
          bF[tj] = *(const long*)(Bsh + c * 8192 + (wc + tj * 16 + mrow) * 64 +
                                  t * 32 + quad * 8);
#pragma unroll
        for (int ti = 0; ti < 4; ++ti)
#pragma unroll
          for (int tj = 0; tj < 4; ++tj)
            acc[ti][tj] = __builtin_amdgcn_mfma_f32_16x16x32_fp8_fp8(
                aF[ti], bF[tj], acc[ti][tj], 0, 0, 0);
      }
    }
  }

  bool is_ss = (bq < 32);
  bool is_tt = (bp >= 32);
  if (!is_ss && !is_tt) {
    // ST: stage rotate-swizzled bf16 v rows of the q (target) tile.
    int rr = tid >> 1, h = (tid & 1) * 16;
    const float* vrow = ws->v + (size_t)(q0 + rr) * 32 + h;
#pragma unroll
    for (int j = 0; j < 16; ++j)
      Vsw[rr * 32 + ((h + j + rr) & 31)] = f2bf(vrow[j]);
  }
  __syncthreads();  // feature-loop LDS reads done; Vsw staged

  float local;
  if (is_ss) {
    if (bp == bq)
      local = epi_ss_st<0, true>(acc, ws, Vsw, p0, q0, wr, wc, mrow, quad);
    else
      local = epi_ss_st<0, false>(acc, ws, Vsw, p0, q0, wr, wc, mrow, quad);
  } else if (!is_tt) {
    local = epi_ss_st<1, false>(acc, ws, Vsw, p0, q0, wr, wc, mrow, quad);
  } else {
    int tp = bp - 32, tq = bq - 32;
    int ttlin = 32 * tp - (tp * (tp - 1)) / 2 + (tq - tp);
    const unsigned short* wttp = ws->wtt + (size_t)ttlin * 16384 + tid * 64;
    if (bp == bq)
      local = epi_tt<true>(acc, ws, wttp, p0, q0, wr, wc, mrow, quad);
    else
      local = epi_tt<false>(acc, ws, wttp, p0, q0, wr, wc, mrow, quad);
  }

  double dl = (double)local;
#pragma unroll
  for (int off = 32; off; off >>= 1) dl += __shfl_down(dl, off, 64);
  double* red = (double*)Ash;  // safe: all Ash reads completed pre-barrier
  if (lane == 0) red[w] = dl;
  __syncthreads();
  if (tid == 0) atomicAdd(&ws->acc_loss, red[0] + red[1] + red[2] + red[3]);
}

__global__ void k4_out(WS* __restrict__ ws, float* __restrict__ out) {
  out[0] = (float)(ws->acc_loss * (double)ws->inv_n_idx);
}

extern "C" void kernel_launch(void* const* d_in, const int* in_sizes, int n_in,
                              void* d_out, int out_size, void* d_ws, size_t ws_size,
                              hipStream_t stream) {
  const float* src = (const float*)d_in[0];
  const float* tgt = (const float*)d_in[1];
  const int* s_label = (const int*)d_in[2];
  const float* t_label = (const float*)d_in[3];
  float* out = (float*)d_out;
  WS* ws = (WS*)d_ws;  // ~21 MB

  k0_init<<<1, 256, 0, stream>>>(ws);
  kA1_stats<<<16, 256, 0, stream>>>(s_label, t_label, ws);
  kA2_final<<<1, 64, 0, stream>>>(ws);
  kB_prep<<<256, 256, 0, stream>>>(src, tgt, s_label, t_label, ws);
  kC_bw<<<1, 64, 0, stream>>>(ws);
  kW_tt<<<NTT, 256, 0, stream>>>(ws);
  k3_main<<<NBLK, 256, 0, stream>>>(ws);
  k4_out<<<1, 1, 0, stream>>>(ws, out);
}

// Round 13
// 169.678 us; speedup vs baseline: 1.1266x; 1.0158x over previous
//
#include <hip/hip_runtime.h>

// LMMD loss, round 13 = round 12 + fp8 LDS conflict fix (granule rotation).
// Within each 64-B sub-row of feature row p, 8-B granule g is stored (in
// GLOBAL layout, so GLD16's linear copy preserves it) at slot (g+p)&7.
// Fragment reads use slot (t*4+quad+R)&7 -> each 16-lane b64 phase covers
// 8 bank-pairs 2-way (free) instead of 2 groups 8-way.
// loss = (1/n_idx) * sum_{p<=q} f_pq * w_pq * K(p,q),  f=2 off-diag, 1 diag
// Features: fp8 e4m3 MFMA (verified round 12: absmax 2.4e-4 < 4.9e-4).
// Weights: SS lookup (exact) / ST LDS gather (bf16) / TT precomputed bf16 tiles.

#define B 4096
#define D 256
#define C 31
#define N2 8192
#define NTILE 64                       // 128-row tiles over 2B rows
#define NBLK (NTILE * (NTILE + 1) / 2) // 2080
#define NTT (32 * 33 / 2)              // 528 TT tile pairs

typedef __attribute__((ext_vector_type(8))) short bf16x8;
typedef __attribute__((ext_vector_type(4))) float f32x4;

struct WS {
  double acc_loss;
  double sum_sq;
  double Msum[256];  // column sums of total (double atomics)
  int s_cnt[32];
  float t_cnt[32];
  int t_pres[32];
  float s_div[32], t_div[32];
  float inv_n_idx;
  float inv_d4;
  float sq[N2];
  int slab[N2];
  float sdv[N2];
  alignas(16) unsigned char Thi8[(size_t)N2 * D];   // fp8 e4m3 (granule-rotated)
  alignas(16) unsigned short vhi[(size_t)N2 * 32];  // bf16 v rows (linear)
  alignas(16) float v[(size_t)N2 * 32];             // exact f32 v rows
  alignas(16) unsigned short wtt[(size_t)NTT * 16384];  // bf16 TT weight tiles
};

static __device__ __forceinline__ unsigned short f2bf(float f) {
  unsigned int u = __float_as_uint(f);
  return (unsigned short)((u + 0x7fffu + ((u >> 16) & 1u)) >> 16);  // RNE
}
static __device__ __forceinline__ float bf2f(unsigned short s) {
  return __uint_as_float(((unsigned int)s) << 16);
}

#define GLD16(gsrc, ldst)                                                     \
  __builtin_amdgcn_global_load_lds(                                           \
      (const __attribute__((address_space(1))) void*)(gsrc),                  \
      (__attribute__((address_space(3))) void*)(ldst), 16, 0, 0)

__global__ void k0_init(WS* __restrict__ ws) {
  int tid = threadIdx.x;  // 256
  if (tid == 0) { ws->acc_loss = 0.0; ws->sum_sq = 0.0; }
  if (tid < 32) {
    ws->s_cnt[tid] = 0;
    ws->t_cnt[tid] = 0.f;
    ws->t_pres[tid] = 0;
  }
  ws->Msum[tid] = 0.0;
}

__global__ void kA1_stats(const int* __restrict__ s_label,
                          const float* __restrict__ t_label,
                          WS* __restrict__ ws) {
  __shared__ int ls[32];
  __shared__ float lt[32];
  __shared__ int lpres[32];
  int tid = threadIdx.x, lane = tid & 63;  // 256, 16 blocks
  if (tid < 32) { ls[tid] = 0; lt[tid] = 0.f; lpres[tid] = 0; }
  __syncthreads();
  int row = blockIdx.x * 256 + tid;
  atomicAdd(&ls[s_label[row]], 1);
  const float* r = t_label + (size_t)row * C;
  float best = -1e30f;
  int barg = 0;
#pragma unroll
  for (int c = 0; c < C; ++c) {
    float x = r[c];
    if (x > best) { best = x; barg = c; }  // first-max == jnp.argmax
    float s = x;
#pragma unroll
    for (int off = 32; off; off >>= 1) s += __shfl_down(s, off, 64);
    if (lane == 0) atomicAdd(&lt[c], s);
  }
  lpres[barg] = 1;  // benign race
  __syncthreads();
  if (tid < 32) {
    if (ls[tid]) atomicAdd(&ws->s_cnt[tid], ls[tid]);
    atomicAdd(&ws->t_cnt[tid], lt[tid]);
    if (lpres[tid]) ws->t_pres[tid] = 1;
  }
}

__global__ void kA2_final(WS* __restrict__ ws) {
  int tid = threadIdx.x;  // 64
  int m = 0;
  if (tid < 32) {
    int cnt = ws->s_cnt[tid];
    m = (tid < C) && (cnt > 0) && (ws->t_pres[tid] != 0);
    ws->s_div[tid] = m ? 1.f / (float)cnt : 0.f;
    float t = ws->t_cnt[tid];
    float ta = (t == 0.f) ? 100.f : t;
    ws->t_div[tid] = m ? 1.f / ta : 0.f;
  }
  unsigned long long bal = __ballot(m);
  if (tid == 0) ws->inv_n_idx = 1.f / fmaxf((float)__popcll(bal), 1.f);
}

__global__ __launch_bounds__(256) void kB_prep(const float* __restrict__ src,
                                               const float* __restrict__ tgt,
                                               const int* __restrict__ s_label,
                                               const float* __restrict__ t_label,
                                               WS* __restrict__ ws) {
  int tid = threadIdx.x, w = tid >> 6, lane = tid & 63;
  int r0 = blockIdx.x * 32;
  __shared__ float rsq[32];
  __shared__ float colp[4][256];
  float ca0 = 0.f, ca1 = 0.f, ca2 = 0.f, ca3 = 0.f;
  // fp8 store position pieces: sub-row sc (64 B), granule gl (8 B), half hf
  int sc = lane >> 4, gl = (lane >> 1) & 7, hf = lane & 1;
#pragma unroll
  for (int i = 0; i < 8; ++i) {
    int rr = w * 8 + i;
    int p = r0 + rr;
    const float* rp = (p < B) ? src + (size_t)p * D : tgt + (size_t)(p - B) * D;
    float4 x = *(const float4*)(rp + lane * 4);
    // fp8 e4m3 pack: byte0=x.x .. byte3=x.w (HW cvt)
    unsigned int pk = __builtin_amdgcn_cvt_pk_fp8_f32(x.x, x.y, 0, false);
    pk = __builtin_amdgcn_cvt_pk_fp8_f32(x.z, x.w, pk, true);
    int gp = (gl + p) & 7;  // granule rotation keyed by row
    *(unsigned int*)(&ws->Thi8[(size_t)p * D + sc * 64 + gp * 8 + hf * 4]) = pk;
    ca0 += x.x; ca1 += x.y; ca2 += x.z; ca3 += x.w;
    float s = x.x * x.x + x.y * x.y + x.z * x.z + x.w * x.w;
#pragma unroll
    for (int off = 32; off; off >>= 1) s += __shfl_down(s, off, 64);
    if (lane == 0) rsq[rr] = s;
  }
  colp[w][lane * 4 + 0] = ca0;
  colp[w][lane * 4 + 1] = ca1;
  colp[w][lane * 4 + 2] = ca2;
  colp[w][lane * 4 + 3] = ca3;
  __syncthreads();
  if (tid < 32) {
    int p = r0 + tid;
    ws->sq[p] = rsq[tid];
    if (p < B) {
      int lb = s_label[p];
      ws->slab[p] = lb;
      ws->sdv[p] = ws->s_div[lb];
    } else {
      ws->slab[p] = 0;
      ws->sdv[p] = 0.f;
    }
  }
  // block sum of sq -> one double atomic (wave 0, all 64 lanes active)
  if (tid < 64) {
    float ss = (tid < 32) ? rsq[tid] : 0.f;
#pragma unroll
    for (int off = 32; off; off >>= 1) ss += __shfl_down(ss, off, 64);
    if (tid == 0) atomicAdd(&ws->sum_sq, (double)ss);
  }
  // column sums -> 256 double atomics per block
  atomicAdd(&ws->Msum[tid],
            (double)(colp[0][tid] + colp[1][tid] + colp[2][tid] + colp[3][tid]));
  int vr = tid >> 3, cb = (tid & 7) * 4;
  int p = r0 + vr;
  float vals[4];
#pragma unroll
  for (int j = 0; j < 4; ++j) {
    int c = cb + j;
    float val = 0.f;
    if (c < C) {
      if (p < B)
        val = (s_label[p] == c) ? ws->s_div[c] : 0.f;
      else
        val = -t_label[(size_t)(p - B) * C + c] * ws->t_div[c];
    }
    vals[j] = val;
  }
  float4 vf; vf.x = vals[0]; vf.y = vals[1]; vf.z = vals[2]; vf.w = vals[3];
  *(float4*)(&ws->v[(size_t)p * 32 + cb]) = vf;
  ushort4 vh;
  vh.x = f2bf(vals[0]); vh.y = f2bf(vals[1]);
  vh.z = f2bf(vals[2]); vh.w = f2bf(vals[3]);
  *(ushort4*)(&ws->vhi[(size_t)p * 32 + cb]) = vh;
}

// One wave: inv_d4 from sum_sq and Msum.
__global__ void kC_bw(WS* __restrict__ ws) {
  int lane = threadIdx.x;  // 64
  double msq = 0.0;
#pragma unroll
  for (int i = 0; i < 4; ++i) {
    double m = ws->Msum[i * 64 + lane];
    msq += m * m;
  }
#pragma unroll
  for (int off = 32; off; off >>= 1) msq += __shfl_down(msq, off, 64);
  if (lane == 0) {
    double S = ws->sum_sq;
    double n = (double)N2;
    double sum_l2 = 2.0 * n * S - 2.0 * msq;
    double bw = sum_l2 / (n * n - n);
    bw = fmax(bw, 1e-6) * 0.25;          // / KERNEL_MUL^2
    double dc4 = fmax(bw * 16.0, 1e-6);  // largest denom
    ws->inv_d4 = (float)(1.0 / dc4);
  }
}

// Precompute TT weight tiles (bf16, stored in C-fragment order). vhi is linear.
__global__ __launch_bounds__(256, 2) void kW_tt(WS* __restrict__ ws) {
  int tid = threadIdx.x, w = tid >> 6, lane = tid & 63;
  int lin = blockIdx.x;
  int tp = 0;
  while (32 * (tp + 1) - ((tp + 1) * tp) / 2 <= lin) ++tp;
  int tq = tp + (lin - (32 * tp - (tp * (tp - 1)) / 2));
  int p0 = B + tp * 128, q0 = B + tq * 128;

  __shared__ __align__(16) unsigned short Ash[128 * 32];
  __shared__ __align__(16) unsigned short Bsh[128 * 32];
  const int wr = (w >> 1) * 64, wc = (w & 1) * 64;
  const int mrow = lane & 15, quad = lane >> 4;
  f32x4 acc[4][4];
#pragma unroll
  for (int i = 0; i < 4; ++i)
#pragma unroll
    for (int j = 0; j < 4; ++j) acc[i][j] = (f32x4){0.f, 0.f, 0.f, 0.f};

  int rA = tid >> 2, cp8 = (tid & 3) * 8;
  unsigned short* ldsA = Ash + w * 512;
  unsigned short* ldsB = Bsh + w * 512;
  const unsigned short* gA = ws->vhi + (size_t)(p0 + rA) * 32 + cp8;
  const unsigned short* gB = ws->vhi + (size_t)(q0 + rA) * 32 + cp8;
  GLD16(gA, ldsA);
  GLD16(gA + (size_t)64 * 32, ldsA + 2048);
  GLD16(gB, ldsB);
  GLD16(gB + (size_t)64 * 32, ldsB + 2048);
  __syncthreads();
  {
    bf16x8 af[4], bfr[4];
#pragma unroll
    for (int ti = 0; ti < 4; ++ti)
      af[ti] = *(const bf16x8*)(Ash + (wr + ti * 16 + mrow) * 32 + quad * 8);
#pragma unroll
    for (int tj = 0; tj < 4; ++tj)
      bfr[tj] = *(const bf16x8*)(Bsh + (wc + tj * 16 + mrow) * 32 + quad * 8);
#pragma unroll
    for (int ti = 0; ti < 4; ++ti)
#pragma unroll
      for (int tj = 0; tj < 4; ++tj)
        acc[ti][tj] = __builtin_amdgcn_mfma_f32_16x16x32_bf16(
            af[ti], bfr[tj], acc[ti][tj], 0, 0, 0);
  }
  unsigned short* out = ws->wtt + (size_t)lin * 16384 + tid * 64;
#pragma unroll
  for (int ti = 0; ti < 4; ++ti)
#pragma unroll
    for (int tj = 0; tj < 4; ++tj) {
      ushort4 u;
      u.x = f2bf(acc[ti][tj][0]);
      u.y = f2bf(acc[ti][tj][1]);
      u.z = f2bf(acc[ti][tj][2]);
      u.w = f2bf(acc[ti][tj][3]);
      *(ushort4*)(out + (ti * 4 + tj) * 4) = u;
    }
}

// ---- epilogue helpers (forceinlined; KIND 0=SS, 1=ST) ----
template <int KIND, bool DIAG>
static __device__ __forceinline__ float epi_ss_st(
    const f32x4 (&acc)[4][4], const WS* __restrict__ ws,
    const unsigned short* Vsw, int p0, int q0, int wr, int wc, int mrow,
    int quad) {
  float cinv = ws->inv_d4;
  float k2 = 2.f * cinv;
  float cq[4], sdq[4];
  int lq[4];
#pragma unroll
  for (int tj = 0; tj < 4; ++tj) {
    int q = q0 + wc + tj * 16 + mrow;
    cq[tj] = -cinv * ws->sq[q];
    if (KIND == 0) {
      lq[tj] = ws->slab[q];
      sdq[tj] = ws->sdv[q];
    }
  }
  float local = 0.f;
#pragma unroll
  for (int ti = 0; ti < 4; ++ti) {
#pragma unroll
    for (int rg = 0; rg < 4; ++rg) {
      int p = p0 + wr + ti * 16 + quad * 4 + rg;
      float cpl = -cinv * ws->sq[p];
      int lp = ws->slab[p];
      float sp = ws->sdv[p];
#pragma unroll
      for (int tj = 0; tj < 4; ++tj) {
        float z = fminf(fmaf(k2, acc[ti][tj][rg], cpl + cq[tj]), 0.f);
        float y = __expf(z);
        float kv = y;
        y *= y; kv += y;
        y *= y; kv += y;
        y *= y; kv += y;
        y *= y; kv += y;
        float wv;
        if (KIND == 0) {
          wv = (lp == lq[tj]) ? sp * sdq[tj] : 0.f;
        } else {
          int ql = wc + tj * 16 + mrow;
          wv = sp * bf2f(Vsw[ql * 32 + ((lp + ql) & 31)]);
        }
        if (DIAG) {
          int q = q0 + wc + tj * 16 + mrow;
          float f = (q > p) ? 2.f : ((q == p) ? 1.f : 0.f);
          local = fmaf(wv * f, kv, local);
        } else {
          local = fmaf(wv, kv, local);
        }
      }
    }
  }
  if (!DIAG) local *= 2.f;
  return local;
}

template <bool DIAG>
static __device__ __forceinline__ float epi_tt(const f32x4 (&acc)[4][4],
                                               const WS* __restrict__ ws,
                                               const unsigned short* wttp,
                                               int p0, int q0, int wr, int wc,
                                               int mrow, int quad) {
  float cinv = ws->inv_d4;
  float k2 = 2.f * cinv;
  float cq[4];
#pragma unroll
  for (int tj = 0; tj < 4; ++tj)
    cq[tj] = -cinv * ws->sq[q0 + wc + tj * 16 + mrow];
  float cp[16];
#pragma unroll
  for (int ti = 0; ti < 4; ++ti)
#pragma unroll
    for (int rg = 0; rg < 4; ++rg)
      cp[ti * 4 + rg] = -cinv * ws->sq[p0 + wr + ti * 16 + quad * 4 + rg];
  float local = 0.f;
#pragma unroll
  for (int ti = 0; ti < 4; ++ti) {
#pragma unroll
    for (int tj = 0; tj < 4; ++tj) {
      ushort4 u = *(const ushort4*)(wttp + (ti * 4 + tj) * 4);
      float wf[4] = {bf2f(u.x), bf2f(u.y), bf2f(u.z), bf2f(u.w)};
#pragma unroll
      for (int rg = 0; rg < 4; ++rg) {
        float z = fminf(fmaf(k2, acc[ti][tj][rg], cp[ti * 4 + rg] + cq[tj]), 0.f);
        float y = __expf(z);
        float kv = y;
        y *= y; kv += y;
        y *= y; kv += y;
        y *= y; kv += y;
        y *= y; kv += y;
        if (DIAG) {
          int p = p0 + wr + ti * 16 + quad * 4 + rg;
          int q = q0 + wc + tj * 16 + mrow;
          float f = (q > p) ? 2.f : ((q == p) ? 1.f : 0.f);
          local = fmaf(wf[rg] * f, kv, local);
        } else {
          local = fmaf(wf[rg], kv, local);
        }
      }
    }
  }
  if (!DIAG) local *= 2.f;
  return local;
}

// Merged main kernel: fp8 features, granule-rotated LDS layout.
// 2 staging stages (K=128 each), 2 chunks per stage -> 2 barrier-drain pairs.
__global__ __launch_bounds__(256, 4) void k3_main(WS* __restrict__ ws) {
  int tid = threadIdx.x, w = tid >> 6, lane = tid & 63;
  int lin0 = blockIdx.x;
  int e = (lin0 & 7) * (NBLK / 8) + (lin0 >> 3);
  int b = 0, nb = 484, rem = e;
  while (rem >= nb) { rem -= nb; ++b; nb -= 64; }
  int base = b * 8;
  int bq_, r;
  if (rem < 36) {  // triangular head of the band (bq within band)
    bq_ = 0;
    while ((bq_ + 1) * (bq_ + 2) / 2 <= rem) ++bq_;
    r = rem - (bq_ * (bq_ + 1)) / 2;
  } else {  // full-height 8-row columns
    int t = rem - 36;
    bq_ = 8 + (t >> 3);
    r = t & 7;
  }
  int bp = base + r, bq = base + bq_;
  int p0 = bp * 128, q0 = bq * 128;

  __shared__ __align__(16) unsigned char Ash[2 * 128 * 64];  // 16 KB fp8 A
  __shared__ __align__(16) unsigned char Bsh[2 * 128 * 64];  // 16 KB fp8 B
  __shared__ unsigned short Vsw[128 * 32];                   // 8 KB (ST only)

  const int wr = (w >> 1) * 64, wc = (w & 1) * 64;
  const int mrow = lane & 15, quad = lane >> 4;
  f32x4 acc[4][4];
#pragma unroll
  for (int i = 0; i < 4; ++i)
#pragma unroll
    for (int j = 0; j < 4; ++j) acc[i][j] = (f32x4){0.f, 0.f, 0.f, 0.f};

  const unsigned char* T8 = ws->Thi8;
  int rA = tid >> 2, cb16 = (tid & 3) * 16;
  unsigned char* ldsA = Ash + w * 1024;
  unsigned char* ldsB = Bsh + w * 1024;

  for (int s = 0; s < 2; ++s) {
    int ks = s * 128;  // byte offset into the 256-B fp8 row
    __syncthreads();
#pragma unroll
    for (int c = 0; c < 2; ++c) {
      const unsigned char* gA =
          T8 + (size_t)(p0 + rA) * D + ks + c * 64 + cb16;
      GLD16(gA, ldsA + c * 8192);
      GLD16(gA + (size_t)64 * D, ldsA + c * 8192 + 4096);
      const unsigned char* gB =
          T8 + (size_t)(q0 + rA) * D + ks + c * 64 + cb16;
      GLD16(gB, ldsB + c * 8192);
      GLD16(gB + (size_t)64 * D, ldsB + c * 8192 + 4096);
    }
    __syncthreads();
#pragma unroll
    for (int c = 0; c < 2; ++c) {
#pragma unroll
      for (int t = 0; t < 2; ++t) {  // two K=32 fp8 MFMA steps per 64-B chunk
        long aF[4], bF[4];
#pragma unroll
        for (int ti = 0; ti < 4; ++ti) {
          int R = wr + ti * 16 + mrow;
          int g = (t * 4 + quad + R) & 7;  // undo granule rotation
          aF[ti] = *(const long*)(Ash + c * 8192 + R * 64 + g * 8);
        }
#pragma unroll
        for (int tj = 0; tj < 4; ++tj) {
          int R = wc + tj * 16 + mrow;
          int g = (t * 4 + quad + R) & 7;
          bF[tj] = *(const long*)(Bsh + c * 8192 + R * 64 + g * 8);
        }
#pragma unroll
        for (int ti = 0; ti < 4; ++ti)
#pragma unroll
          for (int tj = 0; tj < 4; ++tj)
            acc[ti][tj] = __builtin_amdgcn_mfma_f32_16x16x32_fp8_fp8(
                aF[ti], bF[tj], acc[ti][tj], 0, 0, 0);
      }
    }
  }

  bool is_ss = (bq < 32);
  bool is_tt = (bp >= 32);
  if (!is_ss && !is_tt) {
    // ST: stage rotate-swizzled bf16 v rows of the q (target) tile.
    int rr = tid >> 1, h = (tid & 1) * 16;
    const float* vrow = ws->v + (size_t)(q0 + rr) * 32 + h;
#pragma unroll
    for (int j = 0; j < 16; ++j)
      Vsw[rr * 32 + ((h + j + rr) & 31)] = f2bf(vrow[j]);
  }
  __syncthreads();  // feature-loop LDS reads done; Vsw staged

  float local;
  if (is_ss) {
    if (bp == bq)
      local = epi_ss_st<0, true>(acc, ws, Vsw, p0, q0, wr, wc, mrow, quad);
    else
      local = epi_ss_st<0, false>(acc, ws, Vsw, p0, q0, wr, wc, mrow, quad);
  } else if (!is_tt) {
    local = epi_ss_st<1, false>(acc, ws, Vsw, p0, q0, wr, wc, mrow, quad);
  } else {
    int tp = bp - 32, tq = bq - 32;
    int ttlin = 32 * tp - (tp * (tp - 1)) / 2 + (tq - tp);
    const unsigned short* wttp = ws->wtt + (size_t)ttlin * 16384 + tid * 64;
    if (bp == bq)
      local = epi_tt<true>(acc, ws, wttp, p0, q0, wr, wc, mrow, quad);
    else
      local = epi_tt<false>(acc, ws, wttp, p0, q0, wr, wc, mrow, quad);
  }

  double dl = (double)local;
#pragma unroll
  for (int off = 32; off; off >>= 1) dl += __shfl_down(dl, off, 64);
  double* red = (double*)Ash;  // safe: all Ash reads completed pre-barrier
  if (lane == 0) red[w] = dl;
  __syncthreads();
  if (tid == 0) atomicAdd(&ws->acc_loss, red[0] + red[1] + red[2] + red[3]);
}

__global__ void k4_out(WS* __restrict__ ws, float* __restrict__ out) {
  out[0] = (float)(ws->acc_loss * (double)ws->inv_n_idx);
}

extern "C" void kernel_launch(void* const* d_in, const int* in_sizes, int n_in,
                              void* d_out, int out_size, void* d_ws, size_t ws_size,
                              hipStream_t stream) {
  const float* src = (const float*)d_in[0];
  const float* tgt = (const float*)d_in[1];
  const int* s_label = (const int*)d_in[2];
  const float* t_label = (const float*)d_in[3];
  float* out = (float*)d_out;
  WS* ws = (WS*)d_ws;  // ~21 MB

  k0_init<<<1, 256, 0, stream>>>(ws);
  kA1_stats<<<16, 256, 0, stream>>>(s_label, t_label, ws);
  kA2_final<<<1, 64, 0, stream>>>(ws);
  kB_prep<<<256, 256, 0, stream>>>(src, tgt, s_label, t_label, ws);
  kC_bw<<<1, 64, 0, stream>>>(ws);
  kW_tt<<<NTT, 256, 0, stream>>>(ws);
  k3_main<<<NBLK, 256, 0, stream>>>(ws);
  k4_out<<<1, 1, 0, stream>>>(ws, out);
}